// Round 1
// baseline (120.056 us; speedup 1.0000x reference)
//
#include <hip/hip_runtime.h>
#include <hip/hip_bf16.h>

// GCN layer: out[N,16] = segment_sum(vals[e] * embeds[col[e], :], row[e])
// row is sorted -> contiguous runs per row -> register accumulation per run,
// atomicAdd only at run boundaries.

#define D 16
constexpr int BLOCK = 256;
constexpr int GROUPS_PER_BLOCK = BLOCK / D;          // 16 groups of 16 lanes
constexpr int EDGES_PER_GROUP = 128;                 // contiguous edges per group
constexpr int EDGES_PER_BLOCK = GROUPS_PER_BLOCK * EDGES_PER_GROUP;  // 2048

__global__ __launch_bounds__(BLOCK) void gcn_scatter_kernel(
    const int* __restrict__ row, const int* __restrict__ col,
    const float* __restrict__ vals, const float* __restrict__ embeds,
    float* __restrict__ out, int E) {
  __shared__ int   s_row[EDGES_PER_BLOCK];
  __shared__ int   s_col[EDGES_PER_BLOCK];
  __shared__ float s_val[EDGES_PER_BLOCK];

  const long long blockStart = (long long)blockIdx.x * EDGES_PER_BLOCK;

  // Cooperative, coalesced stage of this block's edge metadata into LDS.
  for (int i = threadIdx.x; i < EDGES_PER_BLOCK; i += BLOCK) {
    long long e = blockStart + i;
    if (e < E) {
      s_row[i] = row[e];
      s_col[i] = col[e];
      s_val[i] = vals[e];
    } else {
      s_row[i] = -1;  // sentinel: past end of edge list
    }
  }
  __syncthreads();

  const int g = threadIdx.x >> 4;   // group id within block (0..15)
  const int d = threadIdx.x & 15;   // feature index (0..15)
  const int start = g * EDGES_PER_GROUP;
  const int end   = start + EDGES_PER_GROUP;

  float acc = 0.0f;
  int cur = -1;  // current run's row id

  for (int i = start; i < end; ++i) {
    const int r = s_row[i];
    if (r < 0) break;  // tail block: ran past E
    if (r != cur) {
      if (cur >= 0) atomicAdd(&out[(long long)cur * D + d], acc);
      cur = r;
      acc = 0.0f;
    }
    // 16 lanes of the group read 64 contiguous bytes of embeds (one line).
    acc = fmaf(s_val[i], embeds[(long long)s_col[i] * D + d], acc);
  }
  if (cur >= 0) atomicAdd(&out[(long long)cur * D + d], acc);
}

extern "C" void kernel_launch(void* const* d_in, const int* in_sizes, int n_in,
                              void* d_out, int out_size, void* d_ws, size_t ws_size,
                              hipStream_t stream) {
  const int*   row    = (const int*)d_in[0];
  const int*   col    = (const int*)d_in[1];
  const float* vals   = (const float*)d_in[2];
  const float* embeds = (const float*)d_in[3];
  float*       out    = (float*)d_out;

  const int E = in_sizes[0];

  // Harness poisons d_out (0xAA) and never re-poisons between replays; we
  // accumulate with atomics, so zero the output every call.
  hipMemsetAsync(d_out, 0, (size_t)out_size * sizeof(float), stream);

  const int grid = (int)((E + (long long)EDGES_PER_BLOCK - 1) / EDGES_PER_BLOCK);
  gcn_scatter_kernel<<<grid, BLOCK, 0, stream>>>(row, col, vals, embeds, out, E);
}

// Round 2
// 69.098 us; speedup vs baseline: 1.7375x; 1.7375x over previous
//
#include <hip/hip_runtime.h>
#include <hip/hip_bf16.h>

// GCN layer: out[N,16] = segment_sum(vals[e] * embeds[col[e], :], row[e])
// row sorted -> node-centric: row_ptr via binary search, then each node's
// 4-lane group accumulates its contiguous edge range. No atomics, no memset.

#define D 16
constexpr int BLOCK = 256;

// K1: row_ptr[n] = lower_bound(row, n)  for n in [0, N]  (row_ptr[N] = E)
__global__ __launch_bounds__(BLOCK) void build_row_ptr_kernel(
    const int* __restrict__ row, int E, int* __restrict__ row_ptr, int N) {
  int n = blockIdx.x * BLOCK + threadIdx.x;
  if (n > N) return;
  int lo = 0, hi = E;
  while (lo < hi) {
    int mid = (lo + hi) >> 1;
    if (row[mid] < n) lo = mid + 1; else hi = mid;
  }
  row_ptr[n] = lo;
}

// K2: 4 lanes per node; lane q owns features [4q..4q+3] as float4.
__global__ __launch_bounds__(BLOCK) void gcn_node_kernel(
    const int* __restrict__ col, const float* __restrict__ vals,
    const float4* __restrict__ embeds4, const int* __restrict__ row_ptr,
    float4* __restrict__ out4, int N) {
  int t = blockIdx.x * BLOCK + threadIdx.x;
  int node = t >> 2;
  int q = t & 3;
  if (node >= N) return;

  int beg = row_ptr[node];
  int end = row_ptr[node + 1];

  float4 acc = {0.f, 0.f, 0.f, 0.f};
  #pragma unroll 4
  for (int e = beg; e < end; ++e) {
    int   c = col[e];    // broadcast across the 4-lane group
    float v = vals[e];
    float4 x = embeds4[(long long)c * 4 + q];  // 4 lanes -> 64B contiguous
    acc.x = fmaf(v, x.x, acc.x);
    acc.y = fmaf(v, x.y, acc.y);
    acc.z = fmaf(v, x.z, acc.z);
    acc.w = fmaf(v, x.w, acc.w);
  }
  out4[(long long)node * 4 + q] = acc;  // every output row written (zeros incl.)
}

extern "C" void kernel_launch(void* const* d_in, const int* in_sizes, int n_in,
                              void* d_out, int out_size, void* d_ws, size_t ws_size,
                              hipStream_t stream) {
  const int*   row    = (const int*)d_in[0];
  const int*   col    = (const int*)d_in[1];
  const float* vals   = (const float*)d_in[2];
  const float* embeds = (const float*)d_in[3];
  float*       out    = (float*)d_out;

  const int E = in_sizes[0];
  const int N = in_sizes[3] / D;  // embeds is [N, D]

  int* row_ptr = (int*)d_ws;  // (N+1) ints

  {
    int grid = (N + 1 + BLOCK - 1) / BLOCK;
    build_row_ptr_kernel<<<grid, BLOCK, 0, stream>>>(row, E, row_ptr, N);
  }
  {
    long long threads = (long long)N * 4;
    int grid = (int)((threads + BLOCK - 1) / BLOCK);
    gcn_node_kernel<<<grid, BLOCK, 0, stream>>>(
        col, vals, (const float4*)embeds, row_ptr, (float4*)out, N);
  }
}

// Round 3
// 60.207 us; speedup vs baseline: 1.9941x; 1.1477x over previous
//
#include <hip/hip_runtime.h>
#include <hip/hip_bf16.h>

// GCN layer: out[N,16] = segment_sum(vals[e] * embeds[col[e], :], row[e])
// Node-centric CSR. K1 builds row_ptr by adjacent-diff on sorted row.
// K2: 4 lanes/node, 4-edge aligned chunks -> 4 independent 64B gathers in
// flight per chunk (x2 unroll), breaking the per-edge latency chain.

#define D 16
constexpr int BLOCK = 256;

// K1: row_ptr[n] = first edge with row[e] >= n; row_ptr[N] = E.
// Sorted row -> each thread fills the gap between row[e-1] and row[e].
__global__ __launch_bounds__(BLOCK) void build_row_ptr_kernel(
    const int* __restrict__ row, int E, int* __restrict__ row_ptr, int N) {
  int e = blockIdx.x * BLOCK + threadIdx.x;
  if (e >= E) return;
  int r = row[e];
  int rp = (e == 0) ? -1 : row[e - 1];
  for (int n = rp + 1; n <= r; ++n) row_ptr[n] = e;
  if (e == E - 1) {
    for (int n = r + 1; n <= N; ++n) row_ptr[n] = E;
  }
}

// K2: 4 lanes per node; lane q owns features [4q..4q+3] as one float4.
__global__ __launch_bounds__(BLOCK) void gcn_node_kernel(
    const int* __restrict__ col, const float* __restrict__ vals,
    const float4* __restrict__ embeds4, const int* __restrict__ row_ptr,
    float4* __restrict__ out4, int N, int E) {
  int t = blockIdx.x * BLOCK + threadIdx.x;
  int node = t >> 2;
  int q = t & 3;
  if (node >= N) return;

  int beg = row_ptr[node];
  int end = row_ptr[node + 1];

  float4 acc = {0.f, 0.f, 0.f, 0.f};

  int e0 = beg & ~3;             // 4-aligned chunk start (head masked)
  int e1 = (end + 3) & ~3;       // 4-aligned chunk end   (tail masked)
  if (e1 > E) e1 = E & ~3;       // keep int4/float4 loads in bounds

  #pragma unroll 2
  for (int e = e0; e < e1; e += 4) {
    int4   c4 = *(const int4*)(col + e);     // one aligned 16B load, 4 edges
    float4 v4 = *(const float4*)(vals + e);
    // zero-weight edges outside [beg, end); their gather is a valid index
    // belonging to a neighbor node's edge (cache-hot, harmless).
    float w0 = (e + 0 >= beg && e + 0 < end) ? v4.x : 0.f;
    float w1 = (e + 1 >= beg && e + 1 < end) ? v4.y : 0.f;
    float w2 = (e + 2 >= beg && e + 2 < end) ? v4.z : 0.f;
    float w3 = (e + 3 >= beg && e + 3 < end) ? v4.w : 0.f;
    // 4 independent 64B-per-group gathers -> memory-level parallelism.
    float4 x0 = embeds4[c4.x * 4 + q];
    float4 x1 = embeds4[c4.y * 4 + q];
    float4 x2 = embeds4[c4.z * 4 + q];
    float4 x3 = embeds4[c4.w * 4 + q];
    acc.x = fmaf(w0, x0.x, acc.x);
    acc.y = fmaf(w0, x0.y, acc.y);
    acc.z = fmaf(w0, x0.z, acc.z);
    acc.w = fmaf(w0, x0.w, acc.w);
    acc.x = fmaf(w1, x1.x, acc.x);
    acc.y = fmaf(w1, x1.y, acc.y);
    acc.z = fmaf(w1, x1.z, acc.z);
    acc.w = fmaf(w1, x1.w, acc.w);
    acc.x = fmaf(w2, x2.x, acc.x);
    acc.y = fmaf(w2, x2.y, acc.y);
    acc.z = fmaf(w2, x2.z, acc.z);
    acc.w = fmaf(w2, x2.w, acc.w);
    acc.x = fmaf(w3, x3.x, acc.x);
    acc.y = fmaf(w3, x3.y, acc.y);
    acc.z = fmaf(w3, x3.z, acc.z);
    acc.w = fmaf(w3, x3.w, acc.w);
  }
  // Scalar tail (only reachable if E % 4 != 0).
  for (int e = (e1 > beg ? e1 : beg); e < end; ++e) {
    float  v = vals[e];
    float4 x = embeds4[col[e] * 4 + q];
    acc.x = fmaf(v, x.x, acc.x);
    acc.y = fmaf(v, x.y, acc.y);
    acc.z = fmaf(v, x.z, acc.z);
    acc.w = fmaf(v, x.w, acc.w);
  }

  out4[node * 4 + q] = acc;  // every output row written exactly once
}

extern "C" void kernel_launch(void* const* d_in, const int* in_sizes, int n_in,
                              void* d_out, int out_size, void* d_ws, size_t ws_size,
                              hipStream_t stream) {
  const int*   row    = (const int*)d_in[0];
  const int*   col    = (const int*)d_in[1];
  const float* vals   = (const float*)d_in[2];
  const float* embeds = (const float*)d_in[3];

  const int E = in_sizes[0];
  const int N = in_sizes[3] / D;  // embeds is [N, D]

  int* row_ptr = (int*)d_ws;  // (N+1) ints in workspace

  {
    int grid = (E + BLOCK - 1) / BLOCK;
    build_row_ptr_kernel<<<grid, BLOCK, 0, stream>>>(row, E, row_ptr, N);
  }
  {
    long long threads = (long long)N * 4;
    int grid = (int)((threads + BLOCK - 1) / BLOCK);
    gcn_node_kernel<<<grid, BLOCK, 0, stream>>>(
        col, vals, (const float4*)embeds, row_ptr, (float4*)d_out, N, E);
  }
}

// Round 4
// 56.132 us; speedup vs baseline: 2.1388x; 1.0726x over previous
//
#include <hip/hip_runtime.h>
#include <hip/hip_fp16.h>

// GCN layer: out[N,16] = segment_sum(vals[e] * embeds[col[e], :], row[e])
// Round 4: the gather working set (6.4MB f32) misses the 4MiB/XCD L2 (~64%
// miss rate, 131MB L2-miss traffic). Fix: repack embeds to fp16 (3.2MB ->
// L2-resident per XCD), non-temporal streams for metadata/out so they don't
// evict the table. row_ptr + fp16 table live in d_ws; f32 fallback if ws too
// small.

#define D 16
constexpr int BLOCK = 256;

typedef float f32x4 __attribute__((ext_vector_type(4)));
typedef int   i32x4 __attribute__((ext_vector_type(4)));
typedef unsigned int u32x2 __attribute__((ext_vector_type(2)));
typedef unsigned int u32x4 __attribute__((ext_vector_type(4)));

__device__ inline float2 h2f(unsigned int u) {
  union { unsigned int u; __half2 h; } cv;
  cv.u = u;
  return __half22float2(cv.h);
}

// Fused prep:
//  task A (t < 2N): repack embeds f32 -> f16 table, 8 elems/thread.
//  task B (t < ceil(E/4)): row_ptr[n] = lower_bound(row, n) via adjacent-diff.
__global__ __launch_bounds__(BLOCK) void prep_kernel(
    const int* __restrict__ row, int E,
    const float* __restrict__ embeds, int N,
    int* __restrict__ row_ptr, __half* __restrict__ table) {
  const long long t = (long long)blockIdx.x * BLOCK + threadIdx.x;

  if (table != nullptr) {
    const long long nchunkA = (long long)N * 2;  // 8 halves per chunk
    if (t < nchunkA) {
      const f32x4* src = (const f32x4*)embeds + t * 2;
      f32x4 a = __builtin_nontemporal_load(src);
      f32x4 b = __builtin_nontemporal_load(src + 1);
      union { __half2 h[4]; u32x4 u; } o;
      o.h[0] = __floats2half2_rn(a[0], a[1]);
      o.h[1] = __floats2half2_rn(a[2], a[3]);
      o.h[2] = __floats2half2_rn(b[0], b[1]);
      o.h[3] = __floats2half2_rn(b[2], b[3]);
      *((u32x4*)table + t) = o.u;  // cached store: we WANT this in L2
    }
  }

  const long long e = t * 4;
  if (e < E) {
    int prev = (e == 0) ? -1 : row[e - 1];
    const int cnt = (E - e >= 4) ? 4 : (int)(E - e);
    int r[4];
    if (cnt == 4) {
      i32x4 r4 = __builtin_nontemporal_load((const i32x4*)(row + e));
      r[0] = r4[0]; r[1] = r4[1]; r[2] = r4[2]; r[3] = r4[3];
    } else {
      for (int k = 0; k < cnt; ++k) r[k] = row[e + k];
    }
    for (int k = 0; k < cnt; ++k) {
      for (int n = prev + 1; n <= r[k]; ++n) row_ptr[n] = (int)e + k;
      prev = r[k];
    }
    if (e + cnt == E) {
      for (int n = prev + 1; n <= N; ++n) row_ptr[n] = E;
    }
  }
}

// K2 (fp16 table): 4 lanes/node, lane q owns features [4q..4q+3].
// Gather = 8B (4 halves) per lane; 4 lanes -> one 32B row, L2-resident.
__global__ __launch_bounds__(BLOCK) void gcn_node_half_kernel(
    const int* __restrict__ col, const float* __restrict__ vals,
    const __half* __restrict__ table, const int* __restrict__ row_ptr,
    f32x4* __restrict__ out4, int N, int E) {
  const int t = blockIdx.x * BLOCK + threadIdx.x;
  const int node = t >> 2;
  const int q = t & 3;
  if (node >= N) return;

  const int beg = row_ptr[node];
  const int end = row_ptr[node + 1];

  f32x4 acc = {0.f, 0.f, 0.f, 0.f};

  int e0 = beg & ~3;
  int e1 = (end + 3) & ~3;
  if (e1 > E) e1 = E & ~3;

  #pragma unroll 2
  for (int e = e0; e < e1; e += 4) {
    i32x4 c4 = __builtin_nontemporal_load((const i32x4*)(col + e));
    f32x4 v4 = __builtin_nontemporal_load((const f32x4*)(vals + e));
    float w0 = (e + 0 >= beg && e + 0 < end) ? v4[0] : 0.f;
    float w1 = (e + 1 >= beg && e + 1 < end) ? v4[1] : 0.f;
    float w2 = (e + 2 >= beg && e + 2 < end) ? v4[2] : 0.f;
    float w3 = (e + 3 >= beg && e + 3 < end) ? v4[3] : 0.f;
    // 4 independent 8B gathers (L2-resident fp16 table).
    u32x2 g0 = *(const u32x2*)(table + (long long)c4[0] * 16 + q * 4);
    u32x2 g1 = *(const u32x2*)(table + (long long)c4[1] * 16 + q * 4);
    u32x2 g2 = *(const u32x2*)(table + (long long)c4[2] * 16 + q * 4);
    u32x2 g3 = *(const u32x2*)(table + (long long)c4[3] * 16 + q * 4);
    float2 a0 = h2f(g0[0]), b0 = h2f(g0[1]);
    float2 a1 = h2f(g1[0]), b1 = h2f(g1[1]);
    float2 a2 = h2f(g2[0]), b2 = h2f(g2[1]);
    float2 a3 = h2f(g3[0]), b3 = h2f(g3[1]);
    acc[0] = fmaf(w0, a0.x, acc[0]); acc[1] = fmaf(w0, a0.y, acc[1]);
    acc[2] = fmaf(w0, b0.x, acc[2]); acc[3] = fmaf(w0, b0.y, acc[3]);
    acc[0] = fmaf(w1, a1.x, acc[0]); acc[1] = fmaf(w1, a1.y, acc[1]);
    acc[2] = fmaf(w1, b1.x, acc[2]); acc[3] = fmaf(w1, b1.y, acc[3]);
    acc[0] = fmaf(w2, a2.x, acc[0]); acc[1] = fmaf(w2, a2.y, acc[1]);
    acc[2] = fmaf(w2, b2.x, acc[2]); acc[3] = fmaf(w2, b2.y, acc[3]);
    acc[0] = fmaf(w3, a3.x, acc[0]); acc[1] = fmaf(w3, a3.y, acc[1]);
    acc[2] = fmaf(w3, b3.x, acc[2]); acc[3] = fmaf(w3, b3.y, acc[3]);
  }
  for (int e = (e1 > beg ? e1 : beg); e < end; ++e) {  // tail if E%4 != 0
    float v = vals[e];
    u32x2 g = *(const u32x2*)(table + (long long)col[e] * 16 + q * 4);
    float2 a = h2f(g[0]), b = h2f(g[1]);
    acc[0] = fmaf(v, a.x, acc[0]); acc[1] = fmaf(v, a.y, acc[1]);
    acc[2] = fmaf(v, b.x, acc[2]); acc[3] = fmaf(v, b.y, acc[3]);
  }

  __builtin_nontemporal_store(acc, out4 + (long long)node * 4 + q);
}

// Fallback K2 (f32 gathers straight from embeds) if ws can't hold the table.
__global__ __launch_bounds__(BLOCK) void gcn_node_f32_kernel(
    const int* __restrict__ col, const float* __restrict__ vals,
    const f32x4* __restrict__ embeds4, const int* __restrict__ row_ptr,
    f32x4* __restrict__ out4, int N, int E) {
  const int t = blockIdx.x * BLOCK + threadIdx.x;
  const int node = t >> 2;
  const int q = t & 3;
  if (node >= N) return;
  const int beg = row_ptr[node];
  const int end = row_ptr[node + 1];
  f32x4 acc = {0.f, 0.f, 0.f, 0.f};
  int e0 = beg & ~3;
  int e1 = (end + 3) & ~3;
  if (e1 > E) e1 = E & ~3;
  #pragma unroll 2
  for (int e = e0; e < e1; e += 4) {
    i32x4 c4 = __builtin_nontemporal_load((const i32x4*)(col + e));
    f32x4 v4 = __builtin_nontemporal_load((const f32x4*)(vals + e));
    float w0 = (e + 0 >= beg && e + 0 < end) ? v4[0] : 0.f;
    float w1 = (e + 1 >= beg && e + 1 < end) ? v4[1] : 0.f;
    float w2 = (e + 2 >= beg && e + 2 < end) ? v4[2] : 0.f;
    float w3 = (e + 3 >= beg && e + 3 < end) ? v4[3] : 0.f;
    f32x4 x0 = embeds4[(long long)c4[0] * 4 + q];
    f32x4 x1 = embeds4[(long long)c4[1] * 4 + q];
    f32x4 x2 = embeds4[(long long)c4[2] * 4 + q];
    f32x4 x3 = embeds4[(long long)c4[3] * 4 + q];
    acc += w0 * x0 + w1 * x1;
    acc += w2 * x2 + w3 * x3;
  }
  for (int e = (e1 > beg ? e1 : beg); e < end; ++e) {
    acc += vals[e] * embeds4[(long long)col[e] * 4 + q];
  }
  __builtin_nontemporal_store(acc, out4 + (long long)node * 4 + q);
}

extern "C" void kernel_launch(void* const* d_in, const int* in_sizes, int n_in,
                              void* d_out, int out_size, void* d_ws, size_t ws_size,
                              hipStream_t stream) {
  const int*   row    = (const int*)d_in[0];
  const int*   col    = (const int*)d_in[1];
  const float* vals   = (const float*)d_in[2];
  const float* embeds = (const float*)d_in[3];

  const int E = in_sizes[0];
  const int N = in_sizes[3] / D;

  const size_t rp_bytes = ((size_t)(N + 1) * 4 + 511) & ~(size_t)511;
  const size_t tbl_bytes = (size_t)N * D * sizeof(__half);
  const bool use_half = ws_size >= rp_bytes + tbl_bytes;

  int*    row_ptr = (int*)d_ws;
  __half* table   = use_half ? (__half*)((char*)d_ws + rp_bytes) : nullptr;

  {
    long long chunksB = ((long long)E + 3) / 4;
    long long chunksA = use_half ? (long long)N * 2 : 0;
    long long threads = chunksB > chunksA ? chunksB : chunksA;
    int grid = (int)((threads + BLOCK - 1) / BLOCK);
    prep_kernel<<<grid, BLOCK, 0, stream>>>(row, E, embeds, N, row_ptr, table);
  }
  {
    long long threads = (long long)N * 4;
    int grid = (int)((threads + BLOCK - 1) / BLOCK);
    if (use_half) {
      gcn_node_half_kernel<<<grid, BLOCK, 0, stream>>>(
          col, vals, table, row_ptr, (f32x4*)d_out, N, E);
    } else {
      gcn_node_f32_kernel<<<grid, BLOCK, 0, stream>>>(
          col, vals, (const f32x4*)embeds, row_ptr, (f32x4*)d_out, N, E);
    }
  }
}